// Round 1
// baseline (47.351 us; speedup 1.0000x reference)
//
#include <hip/hip_runtime.h>
#include <hip/hip_bf16.h>

typedef __attribute__((ext_vector_type(4))) float f32x4;
typedef __attribute__((ext_vector_type(8))) short s16x8;

#define M_DIM 256
#define N_DIM 16384
#define K_DIM 2048
#define BM 128
#define BN 128
#define BK 32
#define LDS_PITCH 40          // 32 + 8 bf16 pad: keeps 16B alignment, breaks bank conflicts
#define NKT (K_DIM / BK)      // 64
#define TEMP_INV 20.0f
#define SPECIAL 5554
#define IGNORE_IDX 1023

__device__ __forceinline__ short f2bf(float x) {
  __hip_bfloat16 h = __float2bfloat16(x);
  return __builtin_bit_cast(short, h);
}

__device__ __forceinline__ void cvt_store(short* dst, const float4& f0, const float4& f1) {
  s16x8 h;
  h[0] = f2bf(f0.x); h[1] = f2bf(f0.y); h[2] = f2bf(f0.z); h[3] = f2bf(f0.w);
  h[4] = f2bf(f1.x); h[5] = f2bf(f1.y); h[6] = f2bf(f1.z); h[7] = f2bf(f1.w);
  *reinterpret_cast<s16x8*>(dst) = h;
}

// C[m][n] = sum_k A[m][k] * B[n][k]  (NT gemm), scaled by 1/TEMP, fp32 out.
__global__ __launch_bounds__(512, 1) void gemm_logits(
    const float* __restrict__ A, const float* __restrict__ B,
    float* __restrict__ C) {
  __shared__ __align__(16) short As[2][BM * LDS_PITCH];
  __shared__ __align__(16) short Bs[2][BN * LDS_PITCH];

  // XCD-bijective swizzle (256 blocks % 8 == 0): chunk of 32 logical ids per XCD,
  // consecutive logical ids (2 M-tiles x same N-tile) share the B panel in that XCD's L2.
  int bid = blockIdx.x;
  int lbid = (bid & 7) * 32 + (bid >> 3);
  int bm = lbid & 1;        // 0..1
  int bn = lbid >> 1;       // 0..127

  int tid = threadIdx.x;
  int wave = tid >> 6;
  int lane = tid & 63;
  int wm = wave >> 2;       // 0..1  -> 64 rows
  int wn = wave & 3;        // 0..3  -> 32 cols

  // staging: thread t loads row (t>>2), cols (t&3)*8 .. +8 (two float4)
  int srow = tid >> 2;
  int squad = tid & 3;
  const float* aG = A + (size_t)(bm * BM + srow) * K_DIM + squad * 8;
  const float* bG = B + (size_t)(bn * BN + srow) * K_DIM + squad * 8;
  int swoff = srow * LDS_PITCH + squad * 8;

  f32x4 acc[4][2];
#pragma unroll
  for (int mi = 0; mi < 4; ++mi)
#pragma unroll
    for (int ni = 0; ni < 2; ++ni)
      acc[mi][ni] = f32x4{0.f, 0.f, 0.f, 0.f};

  float4 rA[2][2], rB[2][2];  // [reg set = tile&1][half]; all indices static after unroll

  // prologue: tile0 -> set0 -> buf0 ; issue tile1 -> set1
  rA[0][0] = *(const float4*)(aG);      rA[0][1] = *(const float4*)(aG + 4);
  rB[0][0] = *(const float4*)(bG);      rB[0][1] = *(const float4*)(bG + 4);
  cvt_store(&As[0][swoff], rA[0][0], rA[0][1]);
  cvt_store(&Bs[0][swoff], rB[0][0], rB[0][1]);
  rA[1][0] = *(const float4*)(aG + BK); rA[1][1] = *(const float4*)(aG + BK + 4);
  rB[1][0] = *(const float4*)(bG + BK); rB[1][1] = *(const float4*)(bG + BK + 4);
  __syncthreads();

  int arow0 = (wm * 64 + (lane & 15)) * LDS_PITCH + (lane >> 4) * 8;
  int brow0 = (wn * 32 + (lane & 15)) * LDS_PITCH + (lane >> 4) * 8;

  for (int ktb = 0; ktb < NKT; ktb += 2) {
#pragma unroll
    for (int u = 0; u < 2; ++u) {       // u == kt & 1 (static after unroll)
      int kt = ktb + u;
      const short* asb = &As[u][0];
      const short* bsb = &Bs[u][0];
      s16x8 af[4], bfr[2];
#pragma unroll
      for (int mi = 0; mi < 4; ++mi)
        af[mi] = *reinterpret_cast<const s16x8*>(asb + arow0 + mi * 16 * LDS_PITCH);
#pragma unroll
      for (int ni = 0; ni < 2; ++ni)
        bfr[ni] = *reinterpret_cast<const s16x8*>(bsb + brow0 + ni * 16 * LDS_PITCH);
#pragma unroll
      for (int mi = 0; mi < 4; ++mi)
#pragma unroll
        for (int ni = 0; ni < 2; ++ni)
          acc[mi][ni] = __builtin_amdgcn_mfma_f32_16x16x32_bf16(
              af[mi], bfr[ni], acc[mi][ni], 0, 0, 0);

      if (kt + 1 < NKT) {
        // write tile kt+1 (reg set u^1) into the other LDS buffer
        cvt_store(&As[u ^ 1][swoff], rA[u ^ 1][0], rA[u ^ 1][1]);
        cvt_store(&Bs[u ^ 1][swoff], rB[u ^ 1][0], rB[u ^ 1][1]);
        if (kt + 2 < NKT) {
          const float* ap = aG + (size_t)(kt + 2) * BK;
          const float* bp = bG + (size_t)(kt + 2) * BK;
          rA[u][0] = *(const float4*)ap;  rA[u][1] = *(const float4*)(ap + 4);
          rB[u][0] = *(const float4*)bp;  rB[u][1] = *(const float4*)(bp + 4);
        }
        __syncthreads();
      }
    }
  }

  // epilogue: D row = (lane>>4)*4 + r, col = lane & 15 (m89-verified layout)
  int gm_base = bm * BM + wm * 64 + ((lane >> 4) << 2);
  int gn_base = bn * BN + wn * 32 + (lane & 15);
#pragma unroll
  for (int mi = 0; mi < 4; ++mi)
#pragma unroll
    for (int ni = 0; ni < 2; ++ni)
#pragma unroll
      for (int r = 0; r < 4; ++r)
        C[(size_t)(gm_base + mi * 16 + r) * N_DIM + gn_base + ni * 16] =
            acc[mi][ni][r] * TEMP_INV;
}

// One block per batch row: two-pass max + sumexp over 16384 logits, then nll.
__global__ __launch_bounds__(256) void lse_nll(
    const float* __restrict__ logits, const int* __restrict__ targets,
    float* __restrict__ nll, float* __restrict__ vld) {
  int b = blockIdx.x;
  const float* row = logits + (size_t)b * N_DIM;
  const float4* r4 = reinterpret_cast<const float4*>(row);
  __shared__ float sm[8];
  int tid = threadIdx.x;
  int wid = tid >> 6, lane = tid & 63;

  float mx = -1e30f;
  for (int j = tid; j < N_DIM / 4; j += 256) {
    float4 v = r4[j];
    mx = fmaxf(mx, fmaxf(fmaxf(v.x, v.y), fmaxf(v.z, v.w)));
  }
#pragma unroll
  for (int m = 1; m < 64; m <<= 1) mx = fmaxf(mx, __shfl_xor(mx, m, 64));
  if (lane == 0) sm[wid] = mx;
  __syncthreads();
  if (tid == 0) {
    float m2 = fmaxf(fmaxf(sm[0], sm[1]), fmaxf(sm[2], sm[3]));
    sm[0] = m2;
  }
  __syncthreads();
  mx = sm[0];

  float s = 0.f;
  for (int j = tid; j < N_DIM / 4; j += 256) {
    float4 v = r4[j];
    s += __expf(v.x - mx) + __expf(v.y - mx) + __expf(v.z - mx) + __expf(v.w - mx);
  }
#pragma unroll
  for (int m = 1; m < 64; m <<= 1) s += __shfl_xor(s, m, 64);
  __syncthreads();
  if (lane == 0) sm[wid] = s;
  __syncthreads();
  if (tid == 0) {
    float ss = sm[0] + sm[1] + sm[2] + sm[3];
    int t = targets[b] - 1;
    if (t == SPECIAL) t = IGNORE_IDX;
    bool valid = (t >= 0) && (t != IGNORE_IDX);
    int tc = t < 0 ? 0 : (t > N_DIM - 1 ? N_DIM - 1 : t);
    float lse = mx + __logf(ss);
    float nl = lse - row[tc];
    nll[b] = valid ? nl : 0.0f;
    vld[b] = valid ? 1.0f : 0.0f;
  }
}

__global__ __launch_bounds__(256) void final_reduce(
    const float* __restrict__ nll, const float* __restrict__ vld,
    float* __restrict__ out) {
  int tid = threadIdx.x;
  float s = nll[tid];
  float c = vld[tid];
#pragma unroll
  for (int m = 1; m < 64; m <<= 1) {
    s += __shfl_xor(s, m, 64);
    c += __shfl_xor(c, m, 64);
  }
  __shared__ float ss[4], cc[4];
  int wid = tid >> 6, lane = tid & 63;
  if (lane == 0) { ss[wid] = s; cc[wid] = c; }
  __syncthreads();
  if (tid == 0) {
    float S = ss[0] + ss[1] + ss[2] + ss[3];
    float C = cc[0] + cc[1] + cc[2] + cc[3];
    out[0] = S / fmaxf(C, 1.0f);
  }
}

extern "C" void kernel_launch(void* const* d_in, const int* in_sizes, int n_in,
                              void* d_out, int out_size, void* d_ws, size_t ws_size,
                              hipStream_t stream) {
  const float* inputs   = (const float*)d_in[0];  // [256, 2048]
  const int*   targets  = (const int*)d_in[1];    // [256]
  const float* features = (const float*)d_in[2];  // [16384, 2048]
  float* out = (float*)d_out;

  float* logits = (float*)d_ws;                         // 256*16384 f32 = 16 MB
  float* nll    = logits + (size_t)M_DIM * N_DIM;       // 256 f32
  float* vld    = nll + M_DIM;                          // 256 f32

  gemm_logits<<<dim3(256), dim3(512), 0, stream>>>(inputs, features, logits);
  lse_nll<<<dim3(M_DIM), dim3(256), 0, stream>>>(logits, targets, nll, vld);
  final_reduce<<<dim3(1), dim3(256), 0, stream>>>(nll, vld, out);
}

// Round 2
// 43.036 us; speedup vs baseline: 1.1003x; 1.1003x over previous
//
#include <hip/hip_runtime.h>
#include <hip/hip_bf16.h>

typedef __attribute__((ext_vector_type(4))) float f32x4;
typedef __attribute__((ext_vector_type(8))) short s16x8;

#define M_DIM 256
#define N_DIM 16384
#define K_DIM 2048
#define BM 128
#define BN 128
#define BK 32
#define LDS_PITCH 40          // 32 + 8 bf16 pad: keeps 16B alignment, breaks bank conflicts
#define NKT (K_DIM / BK)      // 64
#define TEMP_INV 20.0f
#define SPECIAL 5554
#define IGNORE_IDX 1023

__device__ __forceinline__ short f2bf(float x) {
  __hip_bfloat16 h = __float2bfloat16(x);
  return __builtin_bit_cast(short, h);
}

__device__ __forceinline__ void cvt_store(short* dst, const float4& f0, const float4& f1) {
  s16x8 h;
  h[0] = f2bf(f0.x); h[1] = f2bf(f0.y); h[2] = f2bf(f0.z); h[3] = f2bf(f0.w);
  h[4] = f2bf(f1.x); h[5] = f2bf(f1.y); h[6] = f2bf(f1.z); h[7] = f2bf(f1.w);
  *reinterpret_cast<s16x8*>(dst) = h;
}

// Fused: C = (A @ B^T)/TEMP ; per-block row partial sum of exp(C) ; target-logit capture.
// Logits are bounded in [-20,20] (unit-norm rows) so exp() needs no max subtraction.
__global__ __launch_bounds__(512, 1) void gemm_fused(
    const float* __restrict__ A, const float* __restrict__ B,
    const int* __restrict__ targets,
    float* __restrict__ partial,   // [128 bn][256 row]
    float* __restrict__ targ) {    // [256]
  __shared__ __align__(16) short As[2][BM * LDS_PITCH];
  __shared__ __align__(16) short Bs[2][BN * LDS_PITCH];
  __shared__ int tcs[BM];          // clipped target col per local row
  __shared__ float rsum[BM][4];    // per-row partial sums, one col per wn-wave

  // XCD-bijective swizzle (256 blocks % 8 == 0): consecutive logical ids
  // (2 bm-tiles x same bn) share the B panel within one XCD's L2.
  int bid = blockIdx.x;
  int lbid = (bid & 7) * 32 + (bid >> 3);
  int bm = lbid & 1;        // 0..1
  int bn = lbid >> 1;       // 0..127

  int tid = threadIdx.x;
  int wave = tid >> 6;
  int lane = tid & 63;
  int wm = wave >> 2;       // 0..1  -> 64 rows
  int wn = wave & 3;        // 0..3  -> 32 cols

  // stage remapped/clipped target columns for this block's 128 rows
  if (tid < BM) {
    int tt = targets[bm * BM + tid] - 1;
    if (tt == SPECIAL) tt = IGNORE_IDX;
    int tc = tt < 0 ? 0 : (tt > N_DIM - 1 ? N_DIM - 1 : tt);
    tcs[tid] = tc;
  }

  // staging: thread t loads row (t>>2), cols (t&3)*8 .. +8 (two float4)
  int srow = tid >> 2;
  int squad = tid & 3;
  const float* aG = A + (size_t)(bm * BM + srow) * K_DIM + squad * 8;
  const float* bG = B + (size_t)(bn * BN + srow) * K_DIM + squad * 8;
  int swoff = srow * LDS_PITCH + squad * 8;

  f32x4 acc[4][2];
#pragma unroll
  for (int mi = 0; mi < 4; ++mi)
#pragma unroll
    for (int ni = 0; ni < 2; ++ni)
      acc[mi][ni] = f32x4{0.f, 0.f, 0.f, 0.f};

  float4 rA[2][2], rB[2][2];  // [reg set = tile&1][half]; static indices after unroll

  rA[0][0] = *(const float4*)(aG);      rA[0][1] = *(const float4*)(aG + 4);
  rB[0][0] = *(const float4*)(bG);      rB[0][1] = *(const float4*)(bG + 4);
  cvt_store(&As[0][swoff], rA[0][0], rA[0][1]);
  cvt_store(&Bs[0][swoff], rB[0][0], rB[0][1]);
  rA[1][0] = *(const float4*)(aG + BK); rA[1][1] = *(const float4*)(aG + BK + 4);
  rB[1][0] = *(const float4*)(bG + BK); rB[1][1] = *(const float4*)(bG + BK + 4);
  __syncthreads();

  int arow0 = (wm * 64 + (lane & 15)) * LDS_PITCH + (lane >> 4) * 8;
  int brow0 = (wn * 32 + (lane & 15)) * LDS_PITCH + (lane >> 4) * 8;

  for (int ktb = 0; ktb < NKT; ktb += 2) {
#pragma unroll
    for (int u = 0; u < 2; ++u) {       // u == kt & 1 (static after unroll)
      int kt = ktb + u;
      const short* asb = &As[u][0];
      const short* bsb = &Bs[u][0];
      s16x8 af[4], bfr[2];
#pragma unroll
      for (int mi = 0; mi < 4; ++mi)
        af[mi] = *reinterpret_cast<const s16x8*>(asb + arow0 + mi * 16 * LDS_PITCH);
#pragma unroll
      for (int ni = 0; ni < 2; ++ni)
        bfr[ni] = *reinterpret_cast<const s16x8*>(bsb + brow0 + ni * 16 * LDS_PITCH);
#pragma unroll
      for (int mi = 0; mi < 4; ++mi)
#pragma unroll
        for (int ni = 0; ni < 2; ++ni)
          acc[mi][ni] = __builtin_amdgcn_mfma_f32_16x16x32_bf16(
              af[mi], bfr[ni], acc[mi][ni], 0, 0, 0);

      if (kt + 1 < NKT) {
        cvt_store(&As[u ^ 1][swoff], rA[u ^ 1][0], rA[u ^ 1][1]);
        cvt_store(&Bs[u ^ 1][swoff], rB[u ^ 1][0], rB[u ^ 1][1]);
        if (kt + 2 < NKT) {
          const float* ap = aG + (size_t)(kt + 2) * BK;
          const float* bp = bG + (size_t)(kt + 2) * BK;
          rA[u][0] = *(const float4*)ap;  rA[u][1] = *(const float4*)(ap + 4);
          rB[u][0] = *(const float4*)bp;  rB[u][1] = *(const float4*)(bp + 4);
        }
        __syncthreads();
      }
    }
  }

  // ---- fused epilogue: exp + per-row reduction + target capture ----
  // D layout (m89-verified): row = mi*16 + (lane>>4)*4 + r, col = ni*16 + (lane&15)
  int g = lane >> 4;              // 0..3
  int cl = lane & 15;             // 0..15
  int gcol_base = bn * BN + wn * 32 + cl;
#pragma unroll
  for (int mi = 0; mi < 4; ++mi) {
#pragma unroll
    for (int r = 0; r < 4; ++r) {
      int rl = wm * 64 + mi * 16 + g * 4 + r;   // local row 0..127
      int tc = tcs[rl];
      float s = 0.f;
#pragma unroll
      for (int ni = 0; ni < 2; ++ni) {
        float logit = acc[mi][ni][r] * TEMP_INV;
        if (gcol_base + ni * 16 == tc) targ[bm * BM + rl] = logit;
        s += __expf(logit);
      }
      // reduce across the 16 col-lanes (masks <16 stay within the group)
#pragma unroll
      for (int m = 1; m < 16; m <<= 1) s += __shfl_xor(s, m, 64);
      if (cl == 0) rsum[rl][wn] = s;
    }
  }
  __syncthreads();
  if (tid < BM) {
    float s = rsum[tid][0] + rsum[tid][1] + rsum[tid][2] + rsum[tid][3];
    partial[(size_t)bn * M_DIM + bm * BM + tid] = s;   // coalesced per final-kernel read
  }
}

__global__ __launch_bounds__(256) void finalize(
    const float* __restrict__ partial, const float* __restrict__ targ,
    const int* __restrict__ targets, float* __restrict__ out) {
  int r = threadIdx.x;   // 256 rows
  float s = 0.f;
  for (int j = 0; j < 128; ++j) s += partial[(size_t)j * M_DIM + r];  // coalesced across threads
  int t = targets[r] - 1;
  if (t == SPECIAL) t = IGNORE_IDX;
  bool valid = (t >= 0) && (t != IGNORE_IDX);
  float nl = logf(s) - targ[r];
  float sv = valid ? nl : 0.0f;
  float cv = valid ? 1.0f : 0.0f;
#pragma unroll
  for (int m = 1; m < 64; m <<= 1) {
    sv += __shfl_xor(sv, m, 64);
    cv += __shfl_xor(cv, m, 64);
  }
  __shared__ float ss[4], cc[4];
  int wid = r >> 6, lane = r & 63;
  if (lane == 0) { ss[wid] = sv; cc[wid] = cv; }
  __syncthreads();
  if (r == 0) {
    float S = ss[0] + ss[1] + ss[2] + ss[3];
    float C = cc[0] + cc[1] + cc[2] + cc[3];
    out[0] = S / fmaxf(C, 1.0f);
  }
}

extern "C" void kernel_launch(void* const* d_in, const int* in_sizes, int n_in,
                              void* d_out, int out_size, void* d_ws, size_t ws_size,
                              hipStream_t stream) {
  const float* inputs   = (const float*)d_in[0];  // [256, 2048]
  const int*   targets  = (const int*)d_in[1];    // [256]
  const float* features = (const float*)d_in[2];  // [16384, 2048]
  float* out = (float*)d_out;

  float* partial = (float*)d_ws;                       // [128][256] f32 = 128 KB
  float* targ    = partial + (size_t)128 * M_DIM;      // [256] f32

  gemm_fused<<<dim3(256), dim3(512), 0, stream>>>(inputs, features, targets, partial, targ);
  finalize<<<dim3(1), dim3(256), 0, stream>>>(partial, targ, targets, out);
}